// Round 12
// baseline (150.405 us; speedup 1.0000x reference)
//
#include <hip/hip_runtime.h>
#include <stdint.h>

// x: [64, 512, 32, 32] f32. 65536 pixels, 512 channels, K=52.
// R6 structure (4096 blocks x 512 thr, [px][ch] LDS tile, 4 blk/CU) with:
//  - ds_write2/ds_read2 pairing (stage 8 instr, extract 8 instr per thread)
//  - no early compact: 3 guarded fixed probes + 2 bisections on u[2][8],
//    window compact (<=32/px) -> dual-pixel 32-lane bitonic -> exact T
//  - fused deterministic last-block reduction (ticket counter memset per call)
// Bounded wave-uniform 31-step bisection fallback => exact for any input.

#define NCH   512
#define K_TOP 52
#define PIX   16
#define NBLK  4096
#define LSTR  516              // row stride words; stage/extract 2-way banks (free)

#define P175  0x3FE00000u
#define P125  0x3FA00000u
#define P0875 0x3F600000u
#define INFB  0x7F800000u

static __device__ __forceinline__ int mbcnt64(uint64_t m) {
    return (int)__builtin_amdgcn_mbcnt_hi((uint32_t)(m >> 32),
            __builtin_amdgcn_mbcnt_lo((uint32_t)m, 0u));
}

__device__ __forceinline__ int cnt8(const uint32_t u[8], uint32_t mb) {
    int c = 0;
    #pragma unroll
    for (int j = 0; j < 8; ++j)
        c += (int)__popcll(__ballot(u[j] >= mb));
    return c;
}

__global__ __launch_bounds__(512, 4) void hah_kernel(const float* __restrict__ x,
                                                     float* __restrict__ ws,
                                                     unsigned* __restrict__ cnt,
                                                     float* __restrict__ out) {
    __shared__ float lds[PIX * LSTR];        // 33 KB tile
    __shared__ uint32_t scr[8][64];          // per-wave sort strips (2 KB)
    __shared__ float red_w[8], red_r[8];
    __shared__ unsigned is_last;

    const int t    = threadIdx.x;
    const int lane = t & 63;
    const int w    = t >> 6;
    const int bid  = blockIdx.x;
    // bijective XCD-chunked swizzle (4096 % 8 == 0)
    const int b    = (bid & 7) * (NBLK >> 3) + (bid >> 3);

    const int pg   = b * PIX;
    const int pix0 = pg & 1023;
    const float* __restrict__ xb = x + (size_t)(pg >> 10) * (NCH * 1024);

    // ---- stage [px][ch] relu'd tile; loads first, paired ds_write2 ----
    const int n_local = t >> 2;              // 0..127
    const int p0      = (t & 3) * 4;         // 0,4,8,12
    float4 vv[4];
    #pragma unroll
    for (int c = 0; c < 4; ++c)
        vv[c] = *reinterpret_cast<const float4*>(xb + (size_t)(n_local + 128 * c) * 1024 + pix0 + p0);

    float relu_acc = 0.0f;
    #pragma unroll
    for (int k = 0; k < 4; ++k) {
        const float r0 = fmaxf(k == 0 ? vv[0].x : k == 1 ? vv[0].y : k == 2 ? vv[0].z : vv[0].w, 0.f);
        const float r1 = fmaxf(k == 0 ? vv[1].x : k == 1 ? vv[1].y : k == 2 ? vv[1].z : vv[1].w, 0.f);
        const float r2 = fmaxf(k == 0 ? vv[2].x : k == 1 ? vv[2].y : k == 2 ? vv[2].z : vv[2].w, 0.f);
        const float r3 = fmaxf(k == 0 ? vv[3].x : k == 1 ? vv[3].y : k == 2 ? vv[3].z : vv[3].w, 0.f);
        float* rb = &lds[(p0 + k) * LSTR + n_local];
        rb[0]   = r0;    // pairs (0,128) and (256,384) -> ds_write2_b32
        rb[128] = r1;
        rb[256] = r2;
        rb[384] = r3;
        relu_acc += (r0 + r1) + (r2 + r3);
    }
    __syncthreads();

    // ---- extract this wave's 2 pixels (paired ds_read2) ----
    const int row = w * 2;
    uint32_t u[2][8];
    #pragma unroll
    for (int i = 0; i < 2; ++i) {
        const float* rb = &lds[(row + i) * LSTR + lane];
        #pragma unroll
        for (int j = 0; j < 8; ++j)
            u[i][j] = __float_as_uint(rb[j * 64]);
    }

    // ---- bracket: 3 guarded fixed probes + 2 adaptive bisections ----
    uint32_t lo[2] = {0u, 0u}, hi[2] = {INFB, INFB};
    int clo[2] = {NCH, NCH}, ctp[2] = {0, 0};
    #pragma unroll
    for (int q = 0; q < 3; ++q) {
        const uint32_t mb = (q == 0) ? P175 : (q == 1) ? P125 : P0875;
        #pragma unroll
        for (int i = 0; i < 2; ++i) {
            const int c = cnt8(u[i], mb);
            const bool valid = (mb > lo[i]) && (mb <= hi[i]);
            const bool ge = valid && (c >= K_TOP);
            const bool lt = valid && (c < K_TOP);
            lo[i] = ge ? mb : lo[i];        clo[i] = ge ? c : clo[i];
            hi[i] = lt ? (mb - 1u) : hi[i]; ctp[i] = lt ? c : ctp[i];
        }
    }
    #pragma unroll
    for (int q = 0; q < 2; ++q) {
        #pragma unroll
        for (int i = 0; i < 2; ++i) {
            const uint32_t mb = (lo[i] + hi[i] + 1u) >> 1;
            const int c = cnt8(u[i], mb);
            const bool ge = (c >= K_TOP);
            lo[i] = ge ? mb : lo[i];        clo[i] = ge ? c : clo[i];
            hi[i] = ge ? hi[i] : (mb - 1u); ctp[i] = ge ? ctp[i] : c;
        }
    }

    const bool wavesmall = (clo[0] - ctp[0] <= 32) && (clo[1] - ctp[1] <= 32);

    uint32_t T[2];
    if (!wavesmall) {
        // bounded exact fallback: 31 bisections converge from any bracket
        #pragma unroll
        for (int i = 0; i < 2; ++i) {
            uint32_t L = lo[i], H = hi[i];
            #pragma unroll 1
            for (int s = 0; s < 31; ++s) {
                const uint32_t mb = (L + H + 1u) >> 1;
                const int c = cnt8(u[i], mb);
                const bool ge = (c >= K_TOP);
                L = ge ? mb : L; H = ge ? H : (mb - 1u);
            }
            T[i] = L;
        }
    } else {
        // window compact (<=32 per px) into the wave strip, then 32-lane bitonic
        scr[w][lane] = 0u;
        #pragma unroll
        for (int i = 0; i < 2; ++i) {
            int base = 0;
            #pragma unroll
            for (int j = 0; j < 8; ++j) {
                const bool pred = (u[i][j] >= lo[i]) && (u[i][j] <= hi[i]);
                const uint64_t mk = __ballot(pred);
                if (pred) scr[w][i * 32 + base + mbcnt64(mk)] = u[i][j];
                base += (int)__popcll(mk);
            }
        }
        uint32_t a = scr[w][lane];
        const int l = lane & 31;
        #pragma unroll
        for (int k = 2; k <= 32; k <<= 1) {
            #pragma unroll
            for (int j = k >> 1; j >= 1; j >>= 1) {
                const bool tm = ((l & k) == 0) == ((l & j) == 0);
                const uint32_t o = (uint32_t)__shfl_xor((int)a, j, 64);
                const uint32_t mx = a > o ? a : o, mn = a > o ? o : a;
                a = tm ? mx : mn;
            }
        }
        T[0] = (uint32_t)__shfl((int)a,      K_TOP - ctp[0] - 1, 64);
        T[1] = (uint32_t)__shfl((int)a, 32 + K_TOP - ctp[1] - 1, 64);
    }

    // ---- tie-exact top-sum on the full set ----
    float sgt = 0.f, topc = 0.f;
    #pragma unroll
    for (int i = 0; i < 2; ++i) {
        const uint32_t Tb = T[i];
        int c = 0;
        #pragma unroll
        for (int j = 0; j < 8; ++j) {
            const bool g = (u[i][j] > Tb);
            c += (int)__popcll(__ballot(g));
            sgt += g ? __uint_as_float(u[i][j]) : 0.f;
        }
        topc += (float)(K_TOP - c) * __uint_as_float(Tb);
    }

    // ---- block partial ----
    #pragma unroll
    for (int m = 32; m >= 1; m >>= 1) {
        sgt      += __shfl_xor(sgt,      m, 64);
        relu_acc += __shfl_xor(relu_acc, m, 64);
    }
    if (lane == 0) { red_w[w] = sgt + topc; red_r[w] = relu_acc; }
    __syncthreads();

    if (t == 0) {
        const float C1 = (1.0f / (float)K_TOP + 1.0f / (float)(NCH - K_TOP));
        const float C2 = (1.0f / (float)(NCH - K_TOP));
        float top = 0.f, s4 = 0.f;
        #pragma unroll
        for (int k = 0; k < 8; ++k) { top += red_w[k]; s4 += red_r[k]; }
        ws[bid] = top * C1 - s4 * C2;
        __threadfence();
        const unsigned old = atomicAdd(cnt, 1u);
        is_last = (old == (unsigned)(NBLK - 1)) ? 1u : 0u;
    }
    __syncthreads();

    // ---- deterministic last-block final reduction ----
    if (is_last) {
        __threadfence();
        float s = 0.f;
        #pragma unroll
        for (int k = 0; k < NBLK / 512; ++k) s += ws[t + 512 * k];
        #pragma unroll
        for (int m = 32; m >= 1; m >>= 1) s += __shfl_xor(s, m, 64);
        if (lane == 0) red_w[w] = s;
        __syncthreads();
        if (t == 0) {
            float tot = 0.f;
            #pragma unroll
            for (int k = 0; k < 8; ++k) tot += red_w[k];
            out[0] = tot * (1.0f / 65536.0f);
        }
    }
}

extern "C" void kernel_launch(void* const* d_in, const int* in_sizes, int n_in,
                              void* d_out, int out_size, void* d_ws, size_t ws_size,
                              hipStream_t stream) {
    const float* x = (const float*)d_in[0];
    float* out = (float*)d_out;
    float* ws  = (float*)d_ws;                       // [0..4095] partials
    unsigned* cnt = (unsigned*)((char*)d_ws + NBLK * sizeof(float));   // ticket

    hipMemsetAsync(cnt, 0, sizeof(unsigned), stream);
    hah_kernel<<<NBLK, 512, 0, stream>>>(x, ws, cnt, out);
}

// Round 13
// 149.869 us; speedup vs baseline: 1.0036x; 1.0036x over previous
//
#include <hip/hip_runtime.h>
#include <stdint.h>

// x: [64, 512, 32, 32] f32. 65536 pixels, 512 channels, K=52.
// R6 kernel (proven 40.9us) verbatim; ONLY change: fused deterministic
// last-block final reduction (atomicAdd ticket, memset per call) replacing
// the separate reduce kernel. Selection: early compact to >=0.75 set (3 regs),
// 2 fixed + 2 adaptive ballot probes, dual-pixel 32-lane bitonic on <=32
// survivors, tie-exact top-sum. Bounded wave-uniform fallbacks => exact always.

#define NCH 512
#define K_TOP 52
#define PIX_PER_BLK 16
#define NBLOCKS 4096
#define LDS_STRIDE 516

#define LO_BITS   0x3F400000u  // 0.75f
#define P175_BITS 0x3FE00000u  // 1.75f
#define P125_BITS 0x3FA00000u  // 1.25f
#define INF_BITS  0x7F800000u
#define CAP_C0    192          // 3 regs * 64 lanes

static __device__ __forceinline__ int mbcnt64(uint64_t m) {
    return (int)__builtin_amdgcn_mbcnt_hi((uint32_t)(m >> 32),
            __builtin_amdgcn_mbcnt_lo((uint32_t)m, 0u));
}

__device__ __forceinline__ int count_ge8(const uint32_t u[8], uint32_t midv) {
    int c = 0;
    #pragma unroll
    for (int j = 0; j < 8; ++j)
        c += (int)__popcll(__ballot(u[j] >= midv));
    return c;
}
__device__ __forceinline__ int count_ge3(const uint32_t c3[3], uint32_t midv) {
    int c = 0;
    #pragma unroll
    for (int j = 0; j < 3; ++j)
        c += (int)__popcll(__ballot(c3[j] >= midv));
    return c;
}
__device__ __forceinline__ void bs_step8(const uint32_t u[8], uint32_t& lo, uint32_t& hi,
                                         int& clo, int& ctop) {
    const uint32_t midv = (lo + hi + 1u) >> 1;
    const int cnt = count_ge8(u, midv);
    const bool ge = (cnt >= K_TOP);
    lo = ge ? midv : lo;        clo  = ge ? cnt  : clo;
    hi = ge ? hi : (midv - 1u); ctop = ge ? ctop : cnt;
}
__device__ __forceinline__ void bs_step3(const uint32_t c3[3], uint32_t& lo, uint32_t& hi,
                                         int& clo, int& ctop) {
    const uint32_t midv = (lo + hi + 1u) >> 1;
    const int cnt = count_ge3(c3, midv);
    const bool ge = (cnt >= K_TOP);
    lo = ge ? midv : lo;        clo  = ge ? cnt  : clo;
    hi = ge ? hi : (midv - 1u); ctop = ge ? ctop : cnt;
}
__device__ __forceinline__ void probe3(const uint32_t c3[3], uint32_t& lo, uint32_t& hi,
                                       int& clo, int& ctop, uint32_t midv) {
    const int cnt = count_ge3(c3, midv);
    const bool valid = (midv > lo) && (midv <= hi);
    const bool ge = valid && (cnt >= K_TOP);
    const bool lt = valid && (cnt < K_TOP);
    lo = ge ? midv : lo;        clo  = ge ? cnt : clo;
    hi = lt ? (midv - 1u) : hi; ctop = lt ? cnt : ctop;
}

__global__ __launch_bounds__(512, 8) void hah_select_kernel(const float* __restrict__ x,
                                                            float* __restrict__ ws,
                                                            unsigned* __restrict__ cnt,
                                                            float* __restrict__ out) {
    __shared__ float lds[PIX_PER_BLK * LDS_STRIDE];   // 33 KB
    __shared__ float red_s[512];
    __shared__ float red_w[8];
    __shared__ unsigned is_last;
    uint32_t* const ldsu = (uint32_t*)lds;

    const int t    = threadIdx.x;
    const int lane = t & 63;
    const int w    = t >> 6;
    const int bid  = blockIdx.x;
    // bijective XCD-chunked swizzle (NBLOCKS % 8 == 0)
    const int b    = (bid & 7) * (NBLOCKS >> 3) + (bid >> 3);

    const int pix_global = b * PIX_PER_BLK;
    const int batch = pix_global >> 10;
    const int pix0  = pix_global & 1023;
    const float* __restrict__ xb = x + (size_t)batch * NCH * 1024;

    // ---- stage [512ch][16px] relu'd tile: ALL loads issued before any write ----
    const int n_local = t >> 2;              // 0..127
    const int p0      = (t & 3) * 4;         // 0,4,8,12
    float4 vv[4];
    #pragma unroll
    for (int c = 0; c < 4; ++c)
        vv[c] = *reinterpret_cast<const float4*>(xb + (size_t)(c * 128 + n_local) * 1024 + pix0 + p0);
    float relu_acc = 0.0f;
    #pragma unroll
    for (int c = 0; c < 4; ++c) {
        const int n = c * 128 + n_local;
        const float r0 = fmaxf(vv[c].x, 0.0f), r1 = fmaxf(vv[c].y, 0.0f);
        const float r2 = fmaxf(vv[c].z, 0.0f), r3 = fmaxf(vv[c].w, 0.0f);
        lds[(p0 + 0) * LDS_STRIDE + n] = r0;
        lds[(p0 + 1) * LDS_STRIDE + n] = r1;
        lds[(p0 + 2) * LDS_STRIDE + n] = r2;
        lds[(p0 + 3) * LDS_STRIDE + n] = r3;
        relu_acc += (r0 + r1) + (r2 + r3);
    }
    red_s[t] = relu_acc;
    __syncthreads();

    // ---- this wave's 2 pixels into registers ----
    const int row = w * 2;
    uint32_t u[2][8];
    #pragma unroll
    for (int i = 0; i < 2; ++i)
        #pragma unroll
        for (int j = 0; j < 8; ++j)
            u[i][j] = __float_as_uint(lds[(row + i) * LDS_STRIDE + j * 64 + lane]);

    int c0[2];
    #pragma unroll
    for (int i = 0; i < 2; ++i) c0[i] = count_ge8(u[i], LO_BITS);

    const bool wavefast =
        (c0[0] >= K_TOP) && (c0[0] <= CAP_C0) && (c0[1] >= K_TOP) && (c0[1] <= CAP_C0);

    float sgt_lane = 0.0f;
    float topc = 0.0f;   // wave-uniform

    if (!wavefast) {
        // ---- exact fallback: full 31-step bisection on the 8-reg set ----
        uint32_t lo[2], hi[2]; int clo[2], ctop[2];
        #pragma unroll
        for (int i = 0; i < 2; ++i) { lo[i] = 0u; hi[i] = INF_BITS; clo[i] = NCH; ctop[i] = 0; }
        #pragma unroll 1
        for (int it = 0; it < 31; ++it) {
            #pragma unroll
            for (int i = 0; i < 2; ++i) bs_step8(u[i], lo[i], hi[i], clo[i], ctop[i]);
        }
        #pragma unroll
        for (int i = 0; i < 2; ++i) {
            const uint32_t T = lo[i];
            const int cgt = count_ge8(u[i], T + 1u);
            #pragma unroll
            for (int j = 0; j < 8; ++j)
                sgt_lane += (u[i][j] > T) ? __uint_as_float(u[i][j]) : 0.0f;
            topc += (float)(K_TOP - cgt) * __uint_as_float(T);
        }
    } else {
        // ---- early compact: values >= 0.75 into this wave's own (dead) LDS rows ----
        #pragma unroll
        for (int i = 0; i < 2; ++i)
            #pragma unroll
            for (int r = 0; r < 3; ++r)
                ldsu[(row + i) * LDS_STRIDE + r * 64 + lane] = 0u;
        #pragma unroll
        for (int i = 0; i < 2; ++i) {
            int base = 0;
            #pragma unroll
            for (int j = 0; j < 8; ++j) {
                const bool pred = (u[i][j] >= LO_BITS);
                const uint64_t mk = __ballot(pred);
                const int pre = mbcnt64(mk);
                if (pred) ldsu[(row + i) * LDS_STRIDE + base + pre] = u[i][j];
                base += (int)__popcll(mk);
            }
        }
        uint32_t c3[2][3];
        #pragma unroll
        for (int i = 0; i < 2; ++i)
            #pragma unroll
            for (int r = 0; r < 3; ++r)
                c3[i][r] = ldsu[(row + i) * LDS_STRIDE + r * 64 + lane];

        // ---- bracket on the compact set: 2 fixed probes + 2 adaptive ----
        uint32_t lo[2], hi[2]; int clo[2], ctop[2];
        #pragma unroll
        for (int i = 0; i < 2; ++i) { lo[i] = LO_BITS; hi[i] = INF_BITS; clo[i] = c0[i]; ctop[i] = 0; }
        #pragma unroll
        for (int i = 0; i < 2; ++i) probe3(c3[i], lo[i], hi[i], clo[i], ctop[i], P175_BITS);
        #pragma unroll
        for (int i = 0; i < 2; ++i) probe3(c3[i], lo[i], hi[i], clo[i], ctop[i], P125_BITS);
        #pragma unroll
        for (int i = 0; i < 2; ++i) bs_step3(c3[i], lo[i], hi[i], clo[i], ctop[i]);
        #pragma unroll
        for (int i = 0; i < 2; ++i) bs_step3(c3[i], lo[i], hi[i], clo[i], ctop[i]);

        const bool wavesmall = (clo[0] - ctop[0] <= 32) && (clo[1] - ctop[1] <= 32);

        uint32_t T[2]; int cgt[2];
        if (!wavesmall) {
            // bounded exact fallback on the compact set
            #pragma unroll 1
            for (int it = 0; it < 31; ++it) {
                #pragma unroll
                for (int i = 0; i < 2; ++i) bs_step3(c3[i], lo[i], hi[i], clo[i], ctop[i]);
            }
            #pragma unroll
            for (int i = 0; i < 2; ++i) { T[i] = lo[i]; cgt[i] = count_ge3(c3[i], lo[i] + 1u); }
        } else {
            // ---- window compact (<=32) then dual-pixel 32-lane bitonic ----
            #pragma unroll
            for (int i = 0; i < 2; ++i)
                ldsu[(row + i) * LDS_STRIDE + 256 + (lane & 31)] = 0u;
            #pragma unroll
            for (int i = 0; i < 2; ++i) {
                int base = 0;
                #pragma unroll
                for (int r = 0; r < 3; ++r) {
                    const bool pred = (c3[i][r] >= lo[i]) && (c3[i][r] <= hi[i]);
                    const uint64_t mk = __ballot(pred);
                    const int pre = mbcnt64(mk);
                    if (pred) ldsu[(row + i) * LDS_STRIDE + 256 + base + pre] = c3[i][r];
                    base += (int)__popcll(mk);
                }
            }
            // px0 candidates -> lanes 0..31, px1 -> lanes 32..63
            uint32_t a = ldsu[(row + (lane >> 5)) * LDS_STRIDE + 256 + (lane & 31)];
            const int l = lane & 31;
            #pragma unroll
            for (int k = 2; k <= 32; k <<= 1) {
                #pragma unroll
                for (int j = k >> 1; j >= 1; j >>= 1) {
                    const bool takeMax = ((l & k) == 0) == ((l & j) == 0);
                    const uint32_t o = (uint32_t)__shfl_xor((int)a, j, 64);
                    const uint32_t mx = a > o ? a : o, mn = a > o ? o : a;
                    a = takeMax ? mx : mn;
                }
            }
            T[0] = (uint32_t)__shfl((int)a,      K_TOP - ctop[0] - 1, 64);
            T[1] = (uint32_t)__shfl((int)a, 32 + K_TOP - ctop[1] - 1, 64);
            const uint32_t tSel = (lane & 32) ? T[1] : T[0];
            const uint64_t mA = __ballot(a > tSel);
            cgt[0] = ctop[0] + (int)__builtin_popcount((uint32_t)mA);
            cgt[1] = ctop[1] + (int)__builtin_popcount((uint32_t)(mA >> 32));
        }

        // ---- tie-exact top-sum from the compact set (all v > T are >= 0.75) ----
        #pragma unroll
        for (int i = 0; i < 2; ++i) {
            #pragma unroll
            for (int r = 0; r < 3; ++r)
                sgt_lane += (c3[i][r] > T[i]) ? __uint_as_float(c3[i][r]) : 0.0f;
            topc += (float)(K_TOP - cgt[i]) * __uint_as_float(T[i]);
        }
    }

    #pragma unroll
    for (int m = 32; m >= 1; m >>= 1)
        sgt_lane += __shfl_xor(sgt_lane, m, 64);
    if (lane == 0) red_w[w] = sgt_lane + topc;
    __syncthreads();

    // ---- block combine: C1 * sum(topsum) - C2 * sum(relu) ----
    if (w == 0) {
        float s4 = 0.0f;
        #pragma unroll
        for (int k = 0; k < 8; ++k) s4 += red_s[lane + 64 * k];
        #pragma unroll
        for (int m = 32; m >= 1; m >>= 1)
            s4 += __shfl_xor(s4, m, 64);
        if (lane == 0) {
            const float C1 = (1.0f / (float)K_TOP + 1.0f / (float)(NCH - K_TOP));
            const float C2 = (1.0f / (float)(NCH - K_TOP));
            float top = 0.0f;
            #pragma unroll
            for (int k = 0; k < 8; ++k) top += red_w[k];
            ws[b] = top * C1 - s4 * C2;
            __threadfence();
            const unsigned old = atomicAdd(cnt, 1u);
            is_last = (old == (unsigned)(NBLOCKS - 1)) ? 1u : 0u;
        }
    }
    __syncthreads();

    // ---- fused deterministic last-block final reduction ----
    if (is_last) {
        __threadfence();
        float s = 0.0f;
        #pragma unroll
        for (int k = 0; k < NBLOCKS / 512; ++k) s += ws[t + 512 * k];
        #pragma unroll
        for (int m = 32; m >= 1; m >>= 1) s += __shfl_xor(s, m, 64);
        __syncthreads();            // red_w reuse: prior readers done
        if (lane == 0) red_w[w] = s;
        __syncthreads();
        if (t == 0) {
            float tot = 0.0f;
            #pragma unroll
            for (int k = 0; k < 8; ++k) tot += red_w[k];
            out[0] = tot * (1.0f / 65536.0f);
        }
    }
}

extern "C" void kernel_launch(void* const* d_in, const int* in_sizes, int n_in,
                              void* d_out, int out_size, void* d_ws, size_t ws_size,
                              hipStream_t stream) {
    const float* x = (const float*)d_in[0];
    float* out = (float*)d_out;
    float* ws  = (float*)d_ws;                                        // 4096 partials
    unsigned* cnt = (unsigned*)((char*)d_ws + NBLOCKS * sizeof(float)); // ticket

    hipMemsetAsync(cnt, 0, sizeof(unsigned), stream);
    hah_select_kernel<<<NBLOCKS, 512, 0, stream>>>(x, ws, cnt, out);
}

// Round 14
// 37.094 us; speedup vs baseline: 4.0547x; 4.0402x over previous
//
#include <hip/hip_runtime.h>
#include <stdint.h>

// x: [64, 512, 32, 32] f32. 65536 pixels, 512 channels, K=52.
// R6 body verbatim; ONLY change: 8-px tiles -> 8192 blocks x 256 thr,
// 16.5 KB LDS, launch_bounds(256,8) = 8 blocks/CU (vs R6's 4) for finer
// stage/select phase interleave across blocks. Two-kernel structure (NO
// atomics/fences - R12/R13 lesson). Selection (R6-proven): early compact to
// >=0.75 set (3 regs), 2 fixed + 2 adaptive ballot probes, dual-pixel 32-lane
// bitonic on <=32 survivors, tie-exact top-sum; bounded wave-uniform
// fallbacks => exact for any input.

#define NCH 512
#define K_TOP 52
#define PIX_PER_BLK 8
#define NBLOCKS 8192
#define LDS_STRIDE 516

#define LO_BITS   0x3F400000u  // 0.75f
#define P175_BITS 0x3FE00000u  // 1.75f
#define P125_BITS 0x3FA00000u  // 1.25f
#define INF_BITS  0x7F800000u
#define CAP_C0    192          // 3 regs * 64 lanes

static __device__ __forceinline__ int mbcnt64(uint64_t m) {
    return (int)__builtin_amdgcn_mbcnt_hi((uint32_t)(m >> 32),
            __builtin_amdgcn_mbcnt_lo((uint32_t)m, 0u));
}

__device__ __forceinline__ int count_ge8(const uint32_t u[8], uint32_t midv) {
    int c = 0;
    #pragma unroll
    for (int j = 0; j < 8; ++j)
        c += (int)__popcll(__ballot(u[j] >= midv));
    return c;
}
__device__ __forceinline__ int count_ge3(const uint32_t c3[3], uint32_t midv) {
    int c = 0;
    #pragma unroll
    for (int j = 0; j < 3; ++j)
        c += (int)__popcll(__ballot(c3[j] >= midv));
    return c;
}
__device__ __forceinline__ void bs_step8(const uint32_t u[8], uint32_t& lo, uint32_t& hi,
                                         int& clo, int& ctop) {
    const uint32_t midv = (lo + hi + 1u) >> 1;
    const int cnt = count_ge8(u, midv);
    const bool ge = (cnt >= K_TOP);
    lo = ge ? midv : lo;        clo  = ge ? cnt  : clo;
    hi = ge ? hi : (midv - 1u); ctop = ge ? ctop : cnt;
}
__device__ __forceinline__ void bs_step3(const uint32_t c3[3], uint32_t& lo, uint32_t& hi,
                                         int& clo, int& ctop) {
    const uint32_t midv = (lo + hi + 1u) >> 1;
    const int cnt = count_ge3(c3, midv);
    const bool ge = (cnt >= K_TOP);
    lo = ge ? midv : lo;        clo  = ge ? cnt  : clo;
    hi = ge ? hi : (midv - 1u); ctop = ge ? ctop : cnt;
}
__device__ __forceinline__ void probe3(const uint32_t c3[3], uint32_t& lo, uint32_t& hi,
                                       int& clo, int& ctop, uint32_t midv) {
    const int cnt = count_ge3(c3, midv);
    const bool valid = (midv > lo) && (midv <= hi);
    const bool ge = valid && (cnt >= K_TOP);
    const bool lt = valid && (cnt < K_TOP);
    lo = ge ? midv : lo;        clo  = ge ? cnt : clo;
    hi = lt ? (midv - 1u) : hi; ctop = lt ? cnt : ctop;
}

__global__ __launch_bounds__(256, 8) void hah_select_kernel(const float* __restrict__ x,
                                                            float* __restrict__ ws) {
    __shared__ float lds[PIX_PER_BLK * LDS_STRIDE];   // 16.5 KB
    __shared__ float red_s[256];
    __shared__ float red_w[4];
    uint32_t* const ldsu = (uint32_t*)lds;

    const int t    = threadIdx.x;
    const int lane = t & 63;
    const int w    = t >> 6;                 // wave 0..3
    const int bid  = blockIdx.x;
    // bijective XCD-chunked swizzle (NBLOCKS % 8 == 0): pixel-adjacent blocks
    // (which share 128B lines) land on the same XCD's L2
    const int b    = (bid & 7) * (NBLOCKS >> 3) + (bid >> 3);

    const int pix_global = b * PIX_PER_BLK;          // 8-aligned, 1024%8==0
    const int batch = pix_global >> 10;
    const int pix0  = pix_global & 1023;
    const float* __restrict__ xb = x + (size_t)batch * NCH * 1024;

    // ---- stage [512ch][8px] relu'd tile: ALL loads issued before any write ----
    const int n_local = t >> 1;              // 0..127
    const int p0      = (t & 1) * 4;         // 0,4
    float4 vv[4];
    #pragma unroll
    for (int c = 0; c < 4; ++c)
        vv[c] = *reinterpret_cast<const float4*>(xb + (size_t)(c * 128 + n_local) * 1024 + pix0 + p0);
    float relu_acc = 0.0f;
    #pragma unroll
    for (int c = 0; c < 4; ++c) {
        const int n = c * 128 + n_local;
        const float r0 = fmaxf(vv[c].x, 0.0f), r1 = fmaxf(vv[c].y, 0.0f);
        const float r2 = fmaxf(vv[c].z, 0.0f), r3 = fmaxf(vv[c].w, 0.0f);
        lds[(p0 + 0) * LDS_STRIDE + n] = r0;
        lds[(p0 + 1) * LDS_STRIDE + n] = r1;
        lds[(p0 + 2) * LDS_STRIDE + n] = r2;
        lds[(p0 + 3) * LDS_STRIDE + n] = r3;
        relu_acc += (r0 + r1) + (r2 + r3);
    }
    red_s[t] = relu_acc;
    __syncthreads();

    // ---- this wave's 2 pixels into registers ----
    const int row = w * 2;                   // rows 0..7
    uint32_t u[2][8];
    #pragma unroll
    for (int i = 0; i < 2; ++i)
        #pragma unroll
        for (int j = 0; j < 8; ++j)
            u[i][j] = __float_as_uint(lds[(row + i) * LDS_STRIDE + j * 64 + lane]);

    int c0[2];
    #pragma unroll
    for (int i = 0; i < 2; ++i) c0[i] = count_ge8(u[i], LO_BITS);

    const bool wavefast =
        (c0[0] >= K_TOP) && (c0[0] <= CAP_C0) && (c0[1] >= K_TOP) && (c0[1] <= CAP_C0);

    float sgt_lane = 0.0f;
    float topc = 0.0f;   // wave-uniform

    if (!wavefast) {
        // ---- exact fallback: full 31-step bisection on the 8-reg set ----
        uint32_t lo[2], hi[2]; int clo[2], ctop[2];
        #pragma unroll
        for (int i = 0; i < 2; ++i) { lo[i] = 0u; hi[i] = INF_BITS; clo[i] = NCH; ctop[i] = 0; }
        #pragma unroll 1
        for (int it = 0; it < 31; ++it) {
            #pragma unroll
            for (int i = 0; i < 2; ++i) bs_step8(u[i], lo[i], hi[i], clo[i], ctop[i]);
        }
        #pragma unroll
        for (int i = 0; i < 2; ++i) {
            const uint32_t T = lo[i];
            const int cgt = count_ge8(u[i], T + 1u);
            #pragma unroll
            for (int j = 0; j < 8; ++j)
                sgt_lane += (u[i][j] > T) ? __uint_as_float(u[i][j]) : 0.0f;
            topc += (float)(K_TOP - cgt) * __uint_as_float(T);
        }
    } else {
        // ---- early compact: values >= 0.75 into this wave's own (dead) LDS rows ----
        #pragma unroll
        for (int i = 0; i < 2; ++i)
            #pragma unroll
            for (int r = 0; r < 3; ++r)
                ldsu[(row + i) * LDS_STRIDE + r * 64 + lane] = 0u;
        #pragma unroll
        for (int i = 0; i < 2; ++i) {
            int base = 0;
            #pragma unroll
            for (int j = 0; j < 8; ++j) {
                const bool pred = (u[i][j] >= LO_BITS);
                const uint64_t mk = __ballot(pred);
                const int pre = mbcnt64(mk);
                if (pred) ldsu[(row + i) * LDS_STRIDE + base + pre] = u[i][j];
                base += (int)__popcll(mk);
            }
        }
        uint32_t c3[2][3];
        #pragma unroll
        for (int i = 0; i < 2; ++i)
            #pragma unroll
            for (int r = 0; r < 3; ++r)
                c3[i][r] = ldsu[(row + i) * LDS_STRIDE + r * 64 + lane];

        // ---- bracket on the compact set: 2 fixed probes + 2 adaptive ----
        uint32_t lo[2], hi[2]; int clo[2], ctop[2];
        #pragma unroll
        for (int i = 0; i < 2; ++i) { lo[i] = LO_BITS; hi[i] = INF_BITS; clo[i] = c0[i]; ctop[i] = 0; }
        #pragma unroll
        for (int i = 0; i < 2; ++i) probe3(c3[i], lo[i], hi[i], clo[i], ctop[i], P175_BITS);
        #pragma unroll
        for (int i = 0; i < 2; ++i) probe3(c3[i], lo[i], hi[i], clo[i], ctop[i], P125_BITS);
        #pragma unroll
        for (int i = 0; i < 2; ++i) bs_step3(c3[i], lo[i], hi[i], clo[i], ctop[i]);
        #pragma unroll
        for (int i = 0; i < 2; ++i) bs_step3(c3[i], lo[i], hi[i], clo[i], ctop[i]);

        const bool wavesmall = (clo[0] - ctop[0] <= 32) && (clo[1] - ctop[1] <= 32);

        uint32_t T[2]; int cgt[2];
        if (!wavesmall) {
            // bounded exact fallback on the compact set
            #pragma unroll 1
            for (int it = 0; it < 31; ++it) {
                #pragma unroll
                for (int i = 0; i < 2; ++i) bs_step3(c3[i], lo[i], hi[i], clo[i], ctop[i]);
            }
            #pragma unroll
            for (int i = 0; i < 2; ++i) { T[i] = lo[i]; cgt[i] = count_ge3(c3[i], lo[i] + 1u); }
        } else {
            // ---- window compact (<=32) then dual-pixel 32-lane bitonic ----
            #pragma unroll
            for (int i = 0; i < 2; ++i)
                ldsu[(row + i) * LDS_STRIDE + 256 + (lane & 31)] = 0u;
            #pragma unroll
            for (int i = 0; i < 2; ++i) {
                int base = 0;
                #pragma unroll
                for (int r = 0; r < 3; ++r) {
                    const bool pred = (c3[i][r] >= lo[i]) && (c3[i][r] <= hi[i]);
                    const uint64_t mk = __ballot(pred);
                    const int pre = mbcnt64(mk);
                    if (pred) ldsu[(row + i) * LDS_STRIDE + 256 + base + pre] = c3[i][r];
                    base += (int)__popcll(mk);
                }
            }
            // px0 candidates -> lanes 0..31, px1 -> lanes 32..63
            uint32_t a = ldsu[(row + (lane >> 5)) * LDS_STRIDE + 256 + (lane & 31)];
            const int l = lane & 31;
            #pragma unroll
            for (int k = 2; k <= 32; k <<= 1) {
                #pragma unroll
                for (int j = k >> 1; j >= 1; j >>= 1) {
                    const bool takeMax = ((l & k) == 0) == ((l & j) == 0);
                    const uint32_t o = (uint32_t)__shfl_xor((int)a, j, 64);
                    const uint32_t mx = a > o ? a : o, mn = a > o ? o : a;
                    a = takeMax ? mx : mn;
                }
            }
            T[0] = (uint32_t)__shfl((int)a,      K_TOP - ctop[0] - 1, 64);
            T[1] = (uint32_t)__shfl((int)a, 32 + K_TOP - ctop[1] - 1, 64);
            const uint32_t tSel = (lane & 32) ? T[1] : T[0];
            const uint64_t mA = __ballot(a > tSel);
            cgt[0] = ctop[0] + (int)__builtin_popcount((uint32_t)mA);
            cgt[1] = ctop[1] + (int)__builtin_popcount((uint32_t)(mA >> 32));
        }

        // ---- tie-exact top-sum from the compact set (all v > T are >= 0.75) ----
        #pragma unroll
        for (int i = 0; i < 2; ++i) {
            #pragma unroll
            for (int r = 0; r < 3; ++r)
                sgt_lane += (c3[i][r] > T[i]) ? __uint_as_float(c3[i][r]) : 0.0f;
            topc += (float)(K_TOP - cgt[i]) * __uint_as_float(T[i]);
        }
    }

    #pragma unroll
    for (int m = 32; m >= 1; m >>= 1)
        sgt_lane += __shfl_xor(sgt_lane, m, 64);
    if (lane == 0) red_w[w] = sgt_lane + topc;
    __syncthreads();

    // ---- block combine: C1 * sum(topsum) - C2 * sum(relu) ----
    if (w == 0) {
        float s4 = red_s[lane] + red_s[lane + 64] + red_s[lane + 128] + red_s[lane + 192];
        #pragma unroll
        for (int m = 32; m >= 1; m >>= 1)
            s4 += __shfl_xor(s4, m, 64);
        if (lane == 0) {
            const float C1 = (1.0f / (float)K_TOP + 1.0f / (float)(NCH - K_TOP));
            const float C2 = (1.0f / (float)(NCH - K_TOP));
            const float top = (red_w[0] + red_w[1]) + (red_w[2] + red_w[3]);
            ws[b] = top * C1 - s4 * C2;
        }
    }
}

__global__ void hah_reduce_kernel(const float* __restrict__ ws, float* __restrict__ out) {
    __shared__ float red[256];
    float s = 0.0f;
    #pragma unroll
    for (int k = 0; k < NBLOCKS / 256; ++k) s += ws[threadIdx.x + 256 * k];
    red[threadIdx.x] = s;
    __syncthreads();
    for (int step = 128; step >= 1; step >>= 1) {
        if (threadIdx.x < step) red[threadIdx.x] += red[threadIdx.x + step];
        __syncthreads();
    }
    if (threadIdx.x == 0) out[0] = red[0] * (1.0f / 65536.0f);
}

extern "C" void kernel_launch(void* const* d_in, const int* in_sizes, int n_in,
                              void* d_out, int out_size, void* d_ws, size_t ws_size,
                              hipStream_t stream) {
    const float* x = (const float*)d_in[0];
    float* out = (float*)d_out;
    float* ws  = (float*)d_ws;   // 8192 float partials (32 KB)

    hah_select_kernel<<<NBLOCKS, 256, 0, stream>>>(x, ws);
    hah_reduce_kernel<<<1, 256, 0, stream>>>(ws, out);
}